// Round 1
// baseline (248.000 us; speedup 1.0000x reference)
//
#include <hip/hip_runtime.h>

// x: (64, 4, 2, 256, 256) f32 ; tensors: (4,4,128,128,2,2,2,2,2) f32 ;
// bias: (4,128,128,2) f32 ; out: (64,4,2,128,128) f32
// sx=sy=256 even -> ix1=2x+1, iy1=2y+1 (clamp inert).
#define NUMN 64
#define CIN 4
#define COUT 4
#define SX 256
#define SY 256
#define NXX 128
#define NYY 128
#define YTILE 8            // R5: one wave owns the block (was 32 / 4 waves)
#define NSPLIT 2
#define NPER (NUMN / NSPLIT)

// R5: single-wave workgroups. The R4 structure barrier-locksteps 4 waves into
// the same LDS-read/VALU phase every iteration (VALUBusy 30%, all pipes <30%).
// With 64-thread blocks the staging producer and consumer are the same wave:
// in-order DS execution + lgkmcnt replaces s_barrier (free in a 1-wave WG),
// and 16 independent blocks/CU decorrelate the phases.
// __launch_bounds__(64,4): cap 128 VGPR (natural ~80, no spill risk); grid
// 4096 = 16 blocks/CU fills residency in one round.
__global__ __launch_bounds__(64, 4)
void ttn_kernel(const float* __restrict__ x, const float* __restrict__ w,
                const float* __restrict__ bias, float* __restrict__ out)
{
    __shared__ float lds[2][256];   // 2 x 1 KB double buffer

    const int bid = blockIdx.x;
    const int xi = bid % NXX;
    const int yt = (bid / NXX) % (NYY / YTILE);
    const int ns = bid / (NXX * (NYY / YTILE));

    const int tid = threadIdx.x;                 // 0..63 (one wave)
    const int yl  = tid & (YTILE - 1);           // 0..7
    const int po  = tid >> 3;                    // p*2 + o
    const int p   = po >> 1;
    const int o   = po & 1;
    const int y   = yt * YTILE + yl;

    // ---- weight preamble: wr[c][q], q = 8i+4j+2k+l (float4 loads) ----
    float wr[CIN][16];
#pragma unroll
    for (int c = 0; c < CIN; ++c) {
        const float4* wp4 = (const float4*)(w +
            ((size_t)(((c * COUT + p) * NXX + xi) * NYY + y)) * 32);
#pragma unroll
        for (int j = 0; j < 8; ++j) {
            const float4 v = wp4[j];
            wr[c][2 * j]     = o ? v.y : v.x;
            wr[c][2 * j + 1] = o ? v.w : v.z;
        }
    }
    const float bv = bias[(((p * NXX + xi) * NYY + y) * 2) + o];

    // ---- staging map: thread -> (chunk mc = (c*2+d)*2 + r, 16B sub-offset) ----
    const int mc   = tid >> 2;                   // 0..15
    const int j0   = (tid & 3) * 4;              // float offset within 16-float chunk
    const int prow = mc >> 1;                    // c*2 + d
    const int r    = mc & 1;                     // which x-row of the pair
    const size_t nstr = (size_t)CIN * 2 * SX * SY;
    const size_t ostr = (size_t)COUT * 2 * NXX * NYY;

    const float* xg = x + (size_t)(ns * NPER) * nstr
                        + ((size_t)prow * SX + (2 * xi + r)) * SY + yt * 16 + j0;
    float* ob = out + (size_t)(ns * NPER) * ostr
                    + (size_t)po * (NXX * NYY) + xi * NYY + y;
    float* ldsw = &lds[0][0] + tid * 4;          // linear ds_write_b128 slot

    float4 P0 = *(const float4*)xg;              // prefetch n=0
    float4 P1 = *(const float4*)(xg + nstr);     // prefetch n=1

    for (int n = 0; n < NPER; ++n) {
        const int cur = n & 1;
        *(float4*)(ldsw + cur * 256) = P0;       // ds_write_b128 (waits only P0)
        P0 = P1;
        const int np = (n + 2 < NPER) ? (n + 2) : (NPER - 1);
        P1 = *(const float4*)(xg + (size_t)np * nstr);  // stays in flight

        __syncthreads();   // 1-wave WG: compiles to lgkmcnt wait, no real barrier

        const float2* l2 = (const float2*)&lds[cur][0];
        float acc = bv;
#pragma unroll
        for (int c = 0; c < CIN; ++c) {
            const float2 ae0 = l2[c * 32 +      yl];   // d0 row0 {a,e}
            const float2 bf0 = l2[c * 32 +  8 + yl];   // d0 row1 {b,f}
            const float2 ae1 = l2[c * 32 + 16 + yl];   // d1 row0 {a,e}
            const float2 bf1 = l2[c * 32 + 24 + yl];   // d1 row1 {b,f}
            const float a0 = ae0.x, e0 = ae0.y, b0 = bf0.x, f0 = bf0.y;
            const float a1 = ae1.x, e1 = ae1.y, b1 = bf1.x, f1 = bf1.y;
            const float ef00 = e0*f0, ef01 = e0*f1, ef10 = e1*f0, ef11 = e1*f1;
            const float ab00 = a0*b0, ab01 = a0*b1, ab10 = a1*b0, ab11 = a1*b1;
            const float* wq = wr[c];
            float t;
            t = ef00*wq[ 0] + ef01*wq[ 1] + ef10*wq[ 2] + ef11*wq[ 3];  acc += ab00 * t;
            t = ef00*wq[ 4] + ef01*wq[ 5] + ef10*wq[ 6] + ef11*wq[ 7];  acc += ab01 * t;
            t = ef00*wq[ 8] + ef01*wq[ 9] + ef10*wq[10] + ef11*wq[11];  acc += ab10 * t;
            t = ef00*wq[12] + ef01*wq[13] + ef10*wq[14] + ef11*wq[15];  acc += ab11 * t;
        }
        ob[(size_t)n * ostr] = acc;
        // dbuf safe without barrier: buf[cur] is rewritten only at n+2; same-wave
        // DS ops execute in order, so iter-n reads complete before that write.
    }
}

extern "C" void kernel_launch(void* const* d_in, const int* in_sizes, int n_in,
                              void* d_out, int out_size, void* d_ws, size_t ws_size,
                              hipStream_t stream) {
    const float* x    = (const float*)d_in[0];
    const float* w    = (const float*)d_in[1];
    const float* bias = (const float*)d_in[2];
    float* out = (float*)d_out;

    const int grid = NXX * (NYY / YTILE) * NSPLIT;  // 128*16*2 = 4096 blocks
    ttn_kernel<<<grid, 64, 0, stream>>>(x, w, bias, out);
}